// Round 2
// baseline (583.138 us; speedup 1.0000x reference)
//
#include <hip/hip_runtime.h>
#include <math.h>

#define NT 256
#define ROWS 128    // rows per block, 2 threads per row

// jax.nn.softplus(x) = max(x,0) + log1p(exp(-|x|))
__device__ __forceinline__ float softplus_f(float v) {
    return fmaxf(v, 0.0f) + log1pf(expf(-fabsf(v)));
}

// LDS layout (float offsets)
#define L_TILE 0        // 8192 floats: 128 rows x 16 float4, rotation-swizzled
#define L_W    8192     // 4096: W[k][j] = sp(EX)-sp(IN)
#define L_H    12288    // 512:  sp(w_hid2out) [64][8]
#define L_C    12800    // 256:  M - sp(w_in2hid) [4][64]
#define L_P4   13056    // 64:   a^4
#define L_Q    13120    // 64:   1+a+a^2+a^3
#define L_TH   13184    // 64:   th_hid
#define L_SM   13248    // 32:   dec_in[4] th_in[4] dec_out[8] th_out[8]
#define L_TOT  13280    // 53120 B -> 3 blocks/CU

__global__ __launch_bounds__(NT) void twc_fused2(
    const float* __restrict__ x,
    const float* __restrict__ hidE0,
    const float* __restrict__ hidO0,
    const float* __restrict__ outE0,
    const float* __restrict__ w_in2hid,
    const float* __restrict__ w_hid_IN,
    const float* __restrict__ w_hid_EX,
    const float* __restrict__ w_hid2out,
    const float* __restrict__ gj_w,
    const float* __restrict__ th_in,
    const float* __restrict__ dec_in,
    const float* __restrict__ th_hid,
    const float* __restrict__ dec_hid,
    const float* __restrict__ th_out,
    const float* __restrict__ dec_out,
    const int* __restrict__ gj_src,
    const int* __restrict__ gj_dst,
    float* __restrict__ out, int B)
{
    __shared__ __align__(16) float s[L_TOT];
    float4* tile4 = (float4*)(s + L_TILE);
    const int t = threadIdx.x;
    const int h = t >> 7;        // column half (uniform per wave: waves 0-1 h=0, 2-3 h=1)
    const int r = t & 127;       // row within tile
    const int rowBase = blockIdx.x * ROWS;
    if (rowBase >= B) return;
    const int b = rowBase + r;

    // swizzled-source index: lds[rr*16 + s] holds g[rr*16 + ((s-rr)&15)]
    auto srcIdx = [&](int j) {
        int i = j * NT + t; int rr = i >> 4; int ss = i & 15;
        return (i & ~15) + ((ss - rr) & 15);
    };

    // ---- issue O0 tile loads early (dense 1KB/wave-inst, permuted within rows) ----
    const float4* gO0 = (const float4*)hidO0 + (size_t)rowBase * 16;
    float4 vin[8];
    #pragma unroll
    for (int j = 0; j < 8; ++j) vin[j] = gO0[srcIdx(j)];

    // ---- weight transform into LDS (latency of vin loads hides under this) ----
    for (int i = t; i < 4096; i += NT)
        s[L_W + i] = softplus_f(w_hid_EX[i]) - softplus_f(w_hid_IN[i]);
    for (int i = t; i < 512; i += NT)
        s[L_H + i] = softplus_f(w_hid2out[i]);
    if (t < 128) {
        s[L_TILE + t]       = softplus_f(gj_w[t]);
        s[L_TILE + 128 + t] = __int_as_float(gj_src[t]);
        s[L_TILE + 256 + t] = __int_as_float(gj_dst[t]);
    }
    if (t < 64) s[L_TH + t] = th_hid[t];
    if (t < 4)  { s[L_SM + t] = dec_in[t]; s[L_SM + 4 + t] = th_in[t]; }
    if (t < 8)  { s[L_SM + 8 + t] = dec_out[t]; s[L_SM + 16 + t] = th_out[t]; }
    __syncthreads();

    // ---- gap-junction scatter -> C, a^4, q ----
    if (t < 64) {
        const int j = t;
        float m0 = 0.f, m1 = 0.f, m2 = 0.f, m3 = 0.f, deg = 0.f;
        #pragma unroll 4
        for (int e = 0; e < 128; ++e) {
            const float w = (__float_as_int(s[L_TILE + 256 + e]) == j) ? s[L_TILE + e] : 0.0f;
            deg += w;
            const int se = __float_as_int(s[L_TILE + 128 + e]);
            m0 += (se == 0) ? w : 0.0f;
            m1 += (se == 1) ? w : 0.0f;
            m2 += (se == 2) ? w : 0.0f;
            m3 += (se == 3) ? w : 0.0f;
        }
        s[L_C + 0*64 + j] = m0 - softplus_f(w_in2hid[0*64 + j]);
        s[L_C + 1*64 + j] = m1 - softplus_f(w_in2hid[1*64 + j]);
        s[L_C + 2*64 + j] = m2 - softplus_f(w_in2hid[2*64 + j]);
        s[L_C + 3*64 + j] = m3 - softplus_f(w_in2hid[3*64 + j]);
        const float a  = dec_hid[j] - deg;
        const float a2 = a * a;
        s[L_P4 + j] = a2 * a2;
        s[L_Q + j]  = 1.0f + a + a2 + a2 * a;
    }
    __syncthreads();

    // ---- write O0 tile (linear dest = dense LDS writes) ----
    #pragma unroll
    for (int j = 0; j < 8; ++j) tile4[j * NT + t] = vin[j];

    const float4 xv = *((const float4*)x + b);
    __syncthreads();

    // ---- I[32] init: x @ C (this thread's 32-col half) ----
    float I[32];
    {
        const float4* C4 = (const float4*)(s + L_C);  // [4][16] f4
        #pragma unroll
        for (int c4 = 0; c4 < 8; ++c4) {
            const int cc = h * 8 + c4;
            const float4 c0 = C4[cc], c1 = C4[16 + cc], c2 = C4[32 + cc], c3 = C4[48 + cc];
            I[4*c4+0] = xv.x*c0.x + xv.y*c1.x + xv.z*c2.x + xv.w*c3.x;
            I[4*c4+1] = xv.x*c0.y + xv.y*c1.y + xv.z*c2.y + xv.w*c3.y;
            I[4*c4+2] = xv.x*c0.z + xv.y*c1.z + xv.z*c2.z + xv.w*c3.z;
            I[4*c4+3] = xv.x*c0.w + xv.y*c1.w + xv.z*c2.w + xv.w*c3.w;
        }
    }

    float h2o[8];
    #pragma unroll
    for (int o = 0; o < 8; ++o) h2o[o] = 0.0f;
    const bool low = (t < 128);   // wave-uniform

    // ---- main matvec: I += O0row @ W[:, half], h2o += O0row @ H (low waves) ----
    {
        const float4* W4 = (const float4*)(s + L_W);  // row stride 16 f4
        const float4* H4 = (const float4*)(s + L_H);  // row stride 2 f4
        #pragma unroll 4
        for (int c4 = 0; c4 < 16; ++c4) {
            const float4 o4 = tile4[r * 16 + ((c4 + r) & 15)];  // O0[r][4c4..4c4+3]
            #pragma unroll
            for (int d = 0; d < 4; ++d) {
                const int k = 4 * c4 + d;
                const float ok = (d == 0) ? o4.x : (d == 1) ? o4.y : (d == 2) ? o4.z : o4.w;
                #pragma unroll
                for (int j4 = 0; j4 < 8; ++j4) {
                    const float4 w = W4[k * 16 + h * 8 + j4];   // wave-uniform broadcast
                    I[4*j4+0] = fmaf(ok, w.x, I[4*j4+0]);
                    I[4*j4+1] = fmaf(ok, w.y, I[4*j4+1]);
                    I[4*j4+2] = fmaf(ok, w.z, I[4*j4+2]);
                    I[4*j4+3] = fmaf(ok, w.w, I[4*j4+3]);
                }
                if (low) {
                    const float4 ha = H4[k*2], hb = H4[k*2+1];
                    h2o[0] = fmaf(ok, ha.x, h2o[0]);
                    h2o[1] = fmaf(ok, ha.y, h2o[1]);
                    h2o[2] = fmaf(ok, ha.z, h2o[2]);
                    h2o[3] = fmaf(ok, ha.w, h2o[3]);
                    h2o[4] = fmaf(ok, hb.x, h2o[4]);
                    h2o[5] = fmaf(ok, hb.y, h2o[5]);
                    h2o[6] = fmaf(ok, hb.z, h2o[6]);
                    h2o[7] = fmaf(ok, hb.w, h2o[7]);
                }
            }
        }
    }

    // ---- stage E0 tile (reuse buffer after O0 consumed) ----
    const float4* gE0 = (const float4*)hidE0 + (size_t)rowBase * 16;
    float4 win[8];
    #pragma unroll
    for (int j = 0; j < 8; ++j) win[j] = gE0[srcIdx(j)];
    __syncthreads();   // everyone done reading O0 tile
    #pragma unroll
    for (int j = 0; j < 8; ++j) tile4[j * NT + t] = win[j];

    float4* outv = (float4*)out;
    const size_t Bs = (size_t)B;

    // ---- per-row outputs (rows owned by low waves; dense stores) ----
    if (low) {
        const float4 di = *(const float4*)(s + L_SM);
        const float4 ti = *(const float4*)(s + L_SM + 4);
        float4 Ein, Oin;
        Ein.x = di.x * xv.x; Ein.y = di.y * xv.y; Ein.z = di.z * xv.z; Ein.w = di.w * xv.w;
        Oin.x = (Ein.x >= ti.x) ? Ein.x : 0.0f;
        Oin.y = (Ein.y >= ti.y) ? Ein.y : 0.0f;
        Oin.z = (Ein.z >= ti.z) ? Ein.z : 0.0f;
        Oin.w = (Ein.w >= ti.w) ? Ein.w : 0.0f;
        outv[Bs * 2 + b] = Ein;
        outv[Bs * 3 + b] = Oin;

        const float4* Eo0 = (const float4*)outE0 + (size_t)b * 2;
        const float4 e0a = Eo0[0], e0b = Eo0[1];
        float Eo[8];
        Eo[0] = fmaf(s[L_SM+8+0], e0a.x, h2o[0]);
        Eo[1] = fmaf(s[L_SM+8+1], e0a.y, h2o[1]);
        Eo[2] = fmaf(s[L_SM+8+2], e0a.z, h2o[2]);
        Eo[3] = fmaf(s[L_SM+8+3], e0a.w, h2o[3]);
        Eo[4] = fmaf(s[L_SM+8+4], e0b.x, h2o[4]);
        Eo[5] = fmaf(s[L_SM+8+5], e0b.y, h2o[5]);
        Eo[6] = fmaf(s[L_SM+8+6], e0b.z, h2o[6]);
        Eo[7] = fmaf(s[L_SM+8+7], e0b.w, h2o[7]);

        float4 a0, a1, Ev0, Ev1, Ov0, Ov1;
        a0.x = tanhf(Eo[0]); a0.y = tanhf(Eo[1]); a0.z = tanhf(Eo[2]); a0.w = tanhf(Eo[3]);
        a1.x = tanhf(Eo[4]); a1.y = tanhf(Eo[5]); a1.z = tanhf(Eo[6]); a1.w = tanhf(Eo[7]);
        Ev0.x = Eo[0]; Ev0.y = Eo[1]; Ev0.z = Eo[2]; Ev0.w = Eo[3];
        Ev1.x = Eo[4]; Ev1.y = Eo[5]; Ev1.z = Eo[6]; Ev1.w = Eo[7];
        Ov0.x = (Eo[0] >= s[L_SM+16+0]) ? Eo[0] : 0.0f;
        Ov0.y = (Eo[1] >= s[L_SM+16+1]) ? Eo[1] : 0.0f;
        Ov0.z = (Eo[2] >= s[L_SM+16+2]) ? Eo[2] : 0.0f;
        Ov0.w = (Eo[3] >= s[L_SM+16+3]) ? Eo[3] : 0.0f;
        Ov1.x = (Eo[4] >= s[L_SM+16+4]) ? Eo[4] : 0.0f;
        Ov1.y = (Eo[5] >= s[L_SM+16+5]) ? Eo[5] : 0.0f;
        Ov1.z = (Eo[6] >= s[L_SM+16+6]) ? Eo[6] : 0.0f;
        Ov1.w = (Eo[7] >= s[L_SM+16+7]) ? Eo[7] : 0.0f;

        outv[(size_t)b*2 + 0] = a0;
        outv[(size_t)b*2 + 1] = a1;
        outv[Bs*36 + (size_t)b*2 + 0] = Ev0;
        outv[Bs*36 + (size_t)b*2 + 1] = Ev1;
        outv[Bs*38 + (size_t)b*2 + 0] = Ov0;
        outv[Bs*38 + (size_t)b*2 + 1] = Ov1;
    }
    __syncthreads();   // E0 tile fully written

    // ---- E_hid: read own E0 slots, write E back to the same slots; keep O in regs ----
    float4 O4[8];
    {
        const float4* P44 = (const float4*)(s + L_P4);
        const float4* Q44 = (const float4*)(s + L_Q);
        const float4* T44 = (const float4*)(s + L_TH);
        #pragma unroll
        for (int c4 = 0; c4 < 8; ++c4) {
            const int cc = h * 8 + c4;
            const int a = r * 16 + ((cc + r) & 15);
            const float4 e0 = tile4[a];
            const float4 p = P44[cc], q = Q44[cc], th = T44[cc];
            float4 E, Ov;
            E.x = fmaf(p.x, e0.x, q.x * I[4*c4+0]);
            E.y = fmaf(p.y, e0.y, q.y * I[4*c4+1]);
            E.z = fmaf(p.z, e0.z, q.z * I[4*c4+2]);
            E.w = fmaf(p.w, e0.w, q.w * I[4*c4+3]);
            Ov.x = (E.x >= th.x) ? E.x : 0.0f;
            Ov.y = (E.y >= th.y) ? E.y : 0.0f;
            Ov.z = (E.z >= th.z) ? E.z : 0.0f;
            Ov.w = (E.w >= th.w) ? E.w : 0.0f;
            tile4[a] = E;      // own slot: no cross-thread hazard
            O4[c4] = Ov;
        }
    }
    __syncthreads();   // all E in tile

    // ---- coalesced copy-out E_hid (dense dwordx4 stores) ----
    {
        const size_t g = Bs * 4 + (size_t)rowBase * 16;
        #pragma unroll
        for (int j = 0; j < 8; ++j) {
            const int i = j * NT + t;
            const int rr = i >> 4, cc = i & 15;
            outv[g + i] = tile4[rr * 16 + ((cc + rr) & 15)];
        }
    }
    __syncthreads();   // copy-out done before overwrite

    // ---- O_hid through the same buffer ----
    #pragma unroll
    for (int c4 = 0; c4 < 8; ++c4) {
        const int cc = h * 8 + c4;
        tile4[r * 16 + ((cc + r) & 15)] = O4[c4];
    }
    __syncthreads();
    {
        const size_t g = Bs * 20 + (size_t)rowBase * 16;
        #pragma unroll
        for (int j = 0; j < 8; ++j) {
            const int i = j * NT + t;
            const int rr = i >> 4, cc = i & 15;
            outv[g + i] = tile4[rr * 16 + ((cc + rr) & 15)];
        }
    }
}

extern "C" void kernel_launch(void* const* d_in, const int* in_sizes, int n_in,
                              void* d_out, int out_size, void* d_ws, size_t ws_size,
                              hipStream_t stream) {
    (void)n_in; (void)out_size; (void)d_ws; (void)ws_size;
    const float* x        = (const float*)d_in[0];
    const float* hidE0    = (const float*)d_in[1];
    const float* hidO0    = (const float*)d_in[2];
    const float* outE0    = (const float*)d_in[3];
    // d_in[4] (out_O0) unused by the reference
    const float* w_in2hid = (const float*)d_in[5];
    const float* w_hid_IN = (const float*)d_in[6];
    const float* w_hid_EX = (const float*)d_in[7];
    const float* w_hid2out= (const float*)d_in[8];
    const float* gj_w     = (const float*)d_in[9];
    const float* th_in    = (const float*)d_in[10];
    const float* dec_in   = (const float*)d_in[11];
    const float* th_hid   = (const float*)d_in[12];
    const float* dec_hid  = (const float*)d_in[13];
    const float* th_out   = (const float*)d_in[14];
    const float* dec_out  = (const float*)d_in[15];
    const int*   gj_src   = (const int*)d_in[16];
    const int*   gj_dst   = (const int*)d_in[17];
    float* out = (float*)d_out;

    const int B = in_sizes[0] / 4;           // 262144; multiple of 128
    const int grid = (B + ROWS - 1) / ROWS;  // 2048
    twc_fused2<<<grid, NT, 0, stream>>>(
        x, hidE0, hidO0, outE0, w_in2hid, w_hid_IN, w_hid_EX, w_hid2out,
        gj_w, th_in, dec_in, th_hid, dec_hid, th_out, dec_out,
        gj_src, gj_dst, out, B);
}

// Round 3
// 302.789 us; speedup vs baseline: 1.9259x; 1.9259x over previous
//
#include <hip/hip_runtime.h>
#include <math.h>

#define NT 256
#define RPB 32          // rows per block; 8 threads per row

// jax.nn.softplus(x) = max(x,0) + log1p(exp(-|x|))
__device__ __forceinline__ float softplus_f(float v) {
    return fmaxf(v, 0.0f) + log1pf(expf(-fabsf(v)));
}

// d_ws layout (float offsets)
#define WS_WH   0         // [64][72]: cols 0..63 = sp(EX)-sp(IN), cols 64..71 = sp(w_hid2out)
#define WS_C    4608      // [4][64]  M - sp(w_in2hid)
#define WS_P4   4864      // [64]     a^4,  a = dec_hid - deg
#define WS_Q    4928      // [64]     1+a+a^2+a^3
#define WS_TH   4992      // [64]     th_hid
#define WS_SM   5056      // dec_in[4] th_in[4] dec_out[8] th_out[8]
#define WS_TOT  5088      // 20352 bytes

__global__ __launch_bounds__(NT) void twc_prep(
    const float* __restrict__ w_in2hid,
    const float* __restrict__ w_hid_IN,
    const float* __restrict__ w_hid_EX,
    const float* __restrict__ w_hid2out,
    const float* __restrict__ gj_w,
    const float* __restrict__ th_in,
    const float* __restrict__ dec_in,
    const float* __restrict__ th_hid,
    const float* __restrict__ dec_hid,
    const float* __restrict__ th_out,
    const float* __restrict__ dec_out,
    const int* __restrict__ gj_src,
    const int* __restrict__ gj_dst,
    float* __restrict__ ws)
{
    const int t = threadIdx.x;
    for (int i = t; i < 4608; i += NT) {
        const int k = i / 72;
        const int j = i - k * 72;
        float v;
        if (j < 64) v = softplus_f(w_hid_EX[k * 64 + j]) - softplus_f(w_hid_IN[k * 64 + j]);
        else        v = softplus_f(w_hid2out[k * 8 + (j - 64)]);
        ws[WS_WH + i] = v;
    }
    if (t < 64) {
        const int j = t;
        float m0 = 0.f, m1 = 0.f, m2 = 0.f, m3 = 0.f, deg = 0.f;
        for (int e = 0; e < 128; ++e) {
            const float w = (gj_dst[e] == j) ? softplus_f(gj_w[e]) : 0.0f;
            deg += w;
            const int se = gj_src[e];
            m0 += (se == 0) ? w : 0.0f;
            m1 += (se == 1) ? w : 0.0f;
            m2 += (se == 2) ? w : 0.0f;
            m3 += (se == 3) ? w : 0.0f;
        }
        ws[WS_C + 0 * 64 + j] = m0 - softplus_f(w_in2hid[0 * 64 + j]);
        ws[WS_C + 1 * 64 + j] = m1 - softplus_f(w_in2hid[1 * 64 + j]);
        ws[WS_C + 2 * 64 + j] = m2 - softplus_f(w_in2hid[2 * 64 + j]);
        ws[WS_C + 3 * 64 + j] = m3 - softplus_f(w_in2hid[3 * 64 + j]);
        const float a  = dec_hid[j] - deg;
        const float a2 = a * a;
        ws[WS_P4 + j] = a2 * a2;
        ws[WS_Q + j]  = 1.0f + a + a2 + a2 * a;
        ws[WS_TH + j] = th_hid[j];
    }
    if (t < 4) { ws[WS_SM + t] = dec_in[t];      ws[WS_SM + 4 + t]  = th_in[t]; }
    if (t < 8) { ws[WS_SM + 8 + t] = dec_out[t]; ws[WS_SM + 16 + t] = th_out[t]; }
}

__global__ __launch_bounds__(NT, 8) void twc_main(
    const float* __restrict__ x,
    const float* __restrict__ hidE0,
    const float* __restrict__ hidO0,
    const float* __restrict__ outE0,
    const float* __restrict__ ws,
    float* __restrict__ out, int B)
{
    __shared__ __align__(16) float4 tile4[RPB * 16];   // 8 KB, rotation-swizzled rows
    const int t = threadIdx.x;
    const int r = t >> 3;        // 0..31: row within tile
    const int q = t & 7;         // 0..7 : column-eighth (8 cols = 2 float4)
    const int rowBase = blockIdx.x * RPB;
    if (rowBase >= B) return;
    const int b = rowBase + r;
    const size_t Bs = (size_t)B;

    const float4* ws4 = (const float4*)ws;
    const int q2 = q * 2;

    // ---- x @ C into I (this thread's 8 columns) ----
    const float4 xv = ((const float4*)x)[b];
    float4 I0, I1;
    {
        const float4 c00 = ws4[WS_C/4 + 0*16 + q2], c01 = ws4[WS_C/4 + 0*16 + q2 + 1];
        const float4 c10 = ws4[WS_C/4 + 1*16 + q2], c11 = ws4[WS_C/4 + 1*16 + q2 + 1];
        const float4 c20 = ws4[WS_C/4 + 2*16 + q2], c21 = ws4[WS_C/4 + 2*16 + q2 + 1];
        const float4 c30 = ws4[WS_C/4 + 3*16 + q2], c31 = ws4[WS_C/4 + 3*16 + q2 + 1];
        I0.x = xv.x*c00.x + xv.y*c10.x + xv.z*c20.x + xv.w*c30.x;
        I0.y = xv.x*c00.y + xv.y*c10.y + xv.z*c20.y + xv.w*c30.y;
        I0.z = xv.x*c00.z + xv.y*c10.z + xv.z*c20.z + xv.w*c30.z;
        I0.w = xv.x*c00.w + xv.y*c10.w + xv.z*c20.w + xv.w*c30.w;
        I1.x = xv.x*c01.x + xv.y*c11.x + xv.z*c21.x + xv.w*c31.x;
        I1.y = xv.x*c01.y + xv.y*c11.y + xv.z*c21.y + xv.w*c31.y;
        I1.z = xv.x*c01.z + xv.y*c11.z + xv.z*c21.z + xv.w*c31.z;
        I1.w = xv.x*c01.w + xv.y*c11.w + xv.z*c21.w + xv.w*c31.w;
    }

    // ---- E_in / O_in early (frees xv) ----
    if (q < 4) {
        const float xq = (q == 0) ? xv.x : (q == 1) ? xv.y : (q == 2) ? xv.z : xv.w;
        const float ein = ws[WS_SM + q] * xq;
        const float oin = (ein >= ws[WS_SM + 4 + q]) ? ein : 0.0f;
        out[Bs * 8  + (size_t)b * 4 + q] = ein;
        out[Bs * 12 + (size_t)b * 4 + q] = oin;
    }

    // ---- main matvec: I += O0row @ W[:,cols], h2o += O0row @ H[:,q] ----
    float h2o = 0.0f;
    {
        const float4* O04 = (const float4*)hidO0 + (size_t)b * 16;
        for (int kk = 0; kk < 16; ++kk) {
            const float4 o4 = O04[kk];
            #pragma unroll
            for (int d = 0; d < 4; ++d) {
                const int k = kk * 4 + d;
                const float ok = (d == 0) ? o4.x : (d == 1) ? o4.y : (d == 2) ? o4.z : o4.w;
                const float4 w0 = ws4[k * 18 + q2];
                const float4 w1 = ws4[k * 18 + q2 + 1];
                I0.x = fmaf(ok, w0.x, I0.x);
                I0.y = fmaf(ok, w0.y, I0.y);
                I0.z = fmaf(ok, w0.z, I0.z);
                I0.w = fmaf(ok, w0.w, I0.w);
                I1.x = fmaf(ok, w1.x, I1.x);
                I1.y = fmaf(ok, w1.y, I1.y);
                I1.z = fmaf(ok, w1.z, I1.z);
                I1.w = fmaf(ok, w1.w, I1.w);
                h2o = fmaf(ok, ws[k * 72 + 64 + q], h2o);
            }
        }
    }

    // ---- output layer (1 column per thread; all stores lane-dense) ----
    {
        const float e0 = outE0[(size_t)b * 8 + q];
        const float eo = fmaf(ws[WS_SM + 8 + q], e0, h2o);
        out[(size_t)b * 8 + q]            = tanhf(eo);
        out[Bs * 144 + (size_t)b * 8 + q] = eo;
        out[Bs * 152 + (size_t)b * 8 + q] = (eo >= ws[WS_SM + 16 + q]) ? eo : 0.0f;
    }

    // ---- stage E0 tile: dense global reads -> swizzled LDS ----
    {
        const float4* E04 = (const float4*)hidE0 + (size_t)rowBase * 16;
        const int i0 = t, i1 = NT + t;
        const float4 ea = E04[i0];
        const float4 eb = E04[i1];
        tile4[(i0 >> 4) * 16 + (((i0 & 15) + (i0 >> 4)) & 15)] = ea;
        tile4[(i1 >> 4) * 16 + (((i1 & 15) + (i1 >> 4)) & 15)] = eb;
    }
    __syncthreads();

    // ---- E_hid = a^4*E0 + (1+a+a^2+a^3)*I, written back into own slots ----
    #pragma unroll
    for (int j4 = 0; j4 < 2; ++j4) {
        const int c = q2 + j4;                  // f4 column 0..15
        const int a = r * 16 + ((c + r) & 15);
        const float4 e0 = tile4[a];
        const float4 p  = ws4[WS_P4/4 + c];
        const float4 qv = ws4[WS_Q/4 + c];
        const float4 Iv = j4 ? I1 : I0;
        float4 E;
        E.x = fmaf(p.x, e0.x, qv.x * Iv.x);
        E.y = fmaf(p.y, e0.y, qv.y * Iv.y);
        E.z = fmaf(p.z, e0.z, qv.z * Iv.z);
        E.w = fmaf(p.w, e0.w, qv.w * Iv.w);
        tile4[a] = E;
    }
    __syncthreads();

    // ---- copy-out: dense E_hid stores; O_hid = gate(E) applied on the fly ----
    {
        float4* out4 = (float4*)out;
        #pragma unroll
        for (int j = 0; j < 2; ++j) {
            const int i = j * NT + t;
            const int rr = i >> 4, cc = i & 15;
            const float4 E = tile4[rr * 16 + ((cc + rr) & 15)];
            const float4 th = ws4[WS_TH/4 + cc];
            float4 O;
            O.x = (E.x >= th.x) ? E.x : 0.0f;
            O.y = (E.y >= th.y) ? E.y : 0.0f;
            O.z = (E.z >= th.z) ? E.z : 0.0f;
            O.w = (E.w >= th.w) ? E.w : 0.0f;
            out4[Bs * 4  + (size_t)rowBase * 16 + i] = E;
            out4[Bs * 20 + (size_t)rowBase * 16 + i] = O;
        }
    }
}

extern "C" void kernel_launch(void* const* d_in, const int* in_sizes, int n_in,
                              void* d_out, int out_size, void* d_ws, size_t ws_size,
                              hipStream_t stream) {
    (void)n_in; (void)out_size; (void)ws_size;
    const float* x        = (const float*)d_in[0];
    const float* hidE0    = (const float*)d_in[1];
    const float* hidO0    = (const float*)d_in[2];
    const float* outE0    = (const float*)d_in[3];
    // d_in[4] (out_O0) unused by the reference
    const float* w_in2hid = (const float*)d_in[5];
    const float* w_hid_IN = (const float*)d_in[6];
    const float* w_hid_EX = (const float*)d_in[7];
    const float* w_hid2out= (const float*)d_in[8];
    const float* gj_w     = (const float*)d_in[9];
    const float* th_in    = (const float*)d_in[10];
    const float* dec_in   = (const float*)d_in[11];
    const float* th_hid   = (const float*)d_in[12];
    const float* dec_hid  = (const float*)d_in[13];
    const float* th_out   = (const float*)d_in[14];
    const float* dec_out  = (const float*)d_in[15];
    const int*   gj_src   = (const int*)d_in[16];
    const int*   gj_dst   = (const int*)d_in[17];
    float* out = (float*)d_out;
    float* ws  = (float*)d_ws;

    const int B = in_sizes[0] / 4;     // 262144, multiple of RPB

    twc_prep<<<1, NT, 0, stream>>>(
        w_in2hid, w_hid_IN, w_hid_EX, w_hid2out, gj_w,
        th_in, dec_in, th_hid, dec_hid, th_out, dec_out,
        gj_src, gj_dst, ws);

    twc_main<<<B / RPB, NT, 0, stream>>>(x, hidE0, hidO0, outE0, ws, out, B);
}

// Round 4
// 173.512 us; speedup vs baseline: 3.3608x; 1.7451x over previous
//
#include <hip/hip_runtime.h>
#include <math.h>

#define NT 256
#define RPB 128         // rows per block
#define NR 4            // rows per thread (strided by 32)

// jax.nn.softplus(x) = max(x,0) + log1p(exp(-|x|))
__device__ __forceinline__ float softplus_f(float v) {
    return fmaxf(v, 0.0f) + log1pf(expf(-fabsf(v)));
}

// ---- d_ws layout (float offsets) ----
// WS_WC: [68][72]; rows 0..63: cols 0..63 = sp(EX)-sp(IN), cols 64..71 = sp(w_hid2out)
//                  rows 64..67: cols 0..63 = C = M - sp(w_in2hid), cols 64..71 = 0
#define WS_WC   0
#define WS_HT   4896      // [8][68]: HT[q][k] = sp(w_hid2out[k][q]) (cols 64..67 unused)
#define WS_P4   5440      // [64] a^4, a = dec_hid - deg
#define WS_Q    5504      // [64] 1+a+a^2+a^3
#define WS_TH   5568      // [64] th_hid
#define WS_SM   5632      // dec_in[4] th_in[4] dec_out[8] th_out[8]
#define WS_TOT  5664

// ---- main-kernel LDS layout ----
// f4 view: W/C rows stride 18 f4 (72 floats); HT f4 base 1224 stride 17; tile f4 base 1360 stride 17
#define LDS_TOT 14144     // floats = 56576 B

__global__ __launch_bounds__(NT) void twc_prep(
    const float* __restrict__ w_in2hid,
    const float* __restrict__ w_hid_IN,
    const float* __restrict__ w_hid_EX,
    const float* __restrict__ w_hid2out,
    const float* __restrict__ gj_w,
    const float* __restrict__ th_in,
    const float* __restrict__ dec_in,
    const float* __restrict__ th_hid,
    const float* __restrict__ dec_hid,
    const float* __restrict__ th_out,
    const float* __restrict__ dec_out,
    const int* __restrict__ gj_src,
    const int* __restrict__ gj_dst,
    float* __restrict__ ws)
{
    const int t = threadIdx.x;
    // W rows 0..63 (+ H cols)
    for (int i = t; i < 4608; i += NT) {
        const int k = i / 72;
        const int j = i - k * 72;
        float v;
        if (j < 64) v = softplus_f(w_hid_EX[k * 64 + j]) - softplus_f(w_hid_IN[k * 64 + j]);
        else        v = softplus_f(w_hid2out[k * 8 + (j - 64)]);
        ws[WS_WC + i] = v;
    }
    // HT[q][k]
    for (int i = t; i < 512; i += NT) {
        const int q = i >> 6, k = i & 63;
        ws[WS_HT + q * 68 + k] = softplus_f(w_hid2out[k * 8 + q]);
    }
    // zero cols 64..71 of C rows
    if (t < 32) ws[WS_WC + (64 + (t >> 3)) * 72 + 64 + (t & 7)] = 0.0f;
    // gap junction scatter -> C rows, a^4, q, th
    if (t < 64) {
        const int j = t;
        float m0 = 0.f, m1 = 0.f, m2 = 0.f, m3 = 0.f, deg = 0.f;
        for (int e = 0; e < 128; ++e) {
            const float w = (gj_dst[e] == j) ? softplus_f(gj_w[e]) : 0.0f;
            deg += w;
            const int se = gj_src[e];
            m0 += (se == 0) ? w : 0.0f;
            m1 += (se == 1) ? w : 0.0f;
            m2 += (se == 2) ? w : 0.0f;
            m3 += (se == 3) ? w : 0.0f;
        }
        ws[WS_WC + (64 + 0) * 72 + j] = m0 - softplus_f(w_in2hid[0 * 64 + j]);
        ws[WS_WC + (64 + 1) * 72 + j] = m1 - softplus_f(w_in2hid[1 * 64 + j]);
        ws[WS_WC + (64 + 2) * 72 + j] = m2 - softplus_f(w_in2hid[2 * 64 + j]);
        ws[WS_WC + (64 + 3) * 72 + j] = m3 - softplus_f(w_in2hid[3 * 64 + j]);
        const float a  = dec_hid[j] - deg;
        const float a2 = a * a;
        ws[WS_P4 + j] = a2 * a2;
        ws[WS_Q + j]  = 1.0f + a + a2 + a2 * a;
        ws[WS_TH + j] = th_hid[j];
    }
    if (t < 4) { ws[WS_SM + t] = dec_in[t];      ws[WS_SM + 4 + t]  = th_in[t]; }
    if (t < 8) { ws[WS_SM + 8 + t] = dec_out[t]; ws[WS_SM + 16 + t] = th_out[t]; }
}

#define FMA8(I0, I1, W0, W1, A)                         \
    I0.x = fmaf(A, W0.x, I0.x); I0.y = fmaf(A, W0.y, I0.y); \
    I0.z = fmaf(A, W0.z, I0.z); I0.w = fmaf(A, W0.w, I0.w); \
    I1.x = fmaf(A, W1.x, I1.x); I1.y = fmaf(A, W1.y, I1.y); \
    I1.z = fmaf(A, W1.z, I1.z); I1.w = fmaf(A, W1.w, I1.w);

__global__ __launch_bounds__(NT, 4) void twc_main(
    const float* __restrict__ x,
    const float* __restrict__ hidE0,
    const float* __restrict__ hidO0,
    const float* __restrict__ outE0,
    const float* __restrict__ ws,
    float* __restrict__ out, int B)
{
    __shared__ __align__(16) float s[LDS_TOT];
    float4* s4 = (float4*)s;
    const float4* ws4 = (const float4*)ws;
    const int t = threadIdx.x;
    const int r = t >> 3;            // 0..31
    const int q = t & 7;             // 0..7
    const size_t rowBase = (size_t)blockIdx.x * RPB;
    const size_t Bs = (size_t)B;
    float4* out4 = (float4*)out;

    // ---- coop stage: weights+HT (1360 f4), O0 tile (2048 f4), x (128 f4) ----
    for (int i = t; i < 1360; i += NT) s4[i] = ws4[i];
    {
        const float4* gO0 = (const float4*)hidO0 + rowBase * 16;
        #pragma unroll
        for (int j = 0; j < 8; ++j) {
            const int i = j * NT + t;
            s4[1360 + (i >> 4) * 17 + (i & 15)] = gO0[i];
        }
        if (t < 128) s4[1360 + t * 17 + 16] = ((const float4*)x)[rowBase + t];
    }
    __syncthreads();

    // ---- k-loop: I[i][8cols] += O0row@W, h2o[i] += O0row@H ----
    float4 I0a, I0b, I1a, I1b, I2a, I2b, I3a, I3b;
    I0a = I0b = I1a = I1b = I2a = I2b = I3a = I3b = float4{0.f, 0.f, 0.f, 0.f};
    float h2o0 = 0.f, h2o1 = 0.f, h2o2 = 0.f, h2o3 = 0.f;

    const int tb = 1360 + r * 17;    // tile f4 base for row r (+ i*544 per row-step of 32)
    const int wq = 2 * q;

    #pragma unroll 2
    for (int kk = 0; kk < 16; ++kk) {
        const float4 o0 = s4[tb + 0 * 544 + kk];
        const float4 o1 = s4[tb + 1 * 544 + kk];
        const float4 o2 = s4[tb + 2 * 544 + kk];
        const float4 o3 = s4[tb + 3 * 544 + kk];
        const float4 ht = s4[1224 + q * 17 + kk];
        #pragma unroll
        for (int d = 0; d < 4; ++d) {
            const int k = 4 * kk + d;
            const float4 w0 = s4[k * 18 + wq];
            const float4 w1 = s4[k * 18 + wq + 1];
            const float hk = (d == 0) ? ht.x : (d == 1) ? ht.y : (d == 2) ? ht.z : ht.w;
            const float a0 = (d == 0) ? o0.x : (d == 1) ? o0.y : (d == 2) ? o0.z : o0.w;
            const float a1 = (d == 0) ? o1.x : (d == 1) ? o1.y : (d == 2) ? o1.z : o1.w;
            const float a2 = (d == 0) ? o2.x : (d == 1) ? o2.y : (d == 2) ? o2.z : o2.w;
            const float a3 = (d == 0) ? o3.x : (d == 1) ? o3.y : (d == 2) ? o3.z : o3.w;
            FMA8(I0a, I0b, w0, w1, a0); h2o0 = fmaf(a0, hk, h2o0);
            FMA8(I1a, I1b, w0, w1, a1); h2o1 = fmaf(a1, hk, h2o1);
            FMA8(I2a, I2b, w0, w1, a2); h2o2 = fmaf(a2, hk, h2o2);
            FMA8(I3a, I3b, w0, w1, a3); h2o3 = fmaf(a3, hk, h2o3);
        }
    }
    // ---- tail: x @ C (C = W rows 64..67) ----
    {
        const float4 x0 = s4[tb + 0 * 544 + 16];
        const float4 x1 = s4[tb + 1 * 544 + 16];
        const float4 x2 = s4[tb + 2 * 544 + 16];
        const float4 x3 = s4[tb + 3 * 544 + 16];
        #pragma unroll
        for (int d = 0; d < 4; ++d) {
            const float4 w0 = s4[(64 + d) * 18 + wq];
            const float4 w1 = s4[(64 + d) * 18 + wq + 1];
            const float a0 = (d == 0) ? x0.x : (d == 1) ? x0.y : (d == 2) ? x0.z : x0.w;
            const float a1 = (d == 0) ? x1.x : (d == 1) ? x1.y : (d == 2) ? x1.z : x1.w;
            const float a2 = (d == 0) ? x2.x : (d == 1) ? x2.y : (d == 2) ? x2.z : x2.w;
            const float a3 = (d == 0) ? x3.x : (d == 1) ? x3.y : (d == 2) ? x3.z : x3.w;
            FMA8(I0a, I0b, w0, w1, a0);
            FMA8(I1a, I1b, w0, w1, a1);
            FMA8(I2a, I2b, w0, w1, a2);
            FMA8(I3a, I3b, w0, w1, a3);
        }
    }

    // ---- E_in / O_in (reads x from tile; before tile reuse) ----
    if (t < 128) {
        const float4 xv = s4[1360 + t * 17 + 16];
        const float4 di = ws4[1408];   // dec_in
        const float4 ti = ws4[1409];   // th_in
        float4 Ein, Oin;
        Ein.x = di.x * xv.x; Ein.y = di.y * xv.y; Ein.z = di.z * xv.z; Ein.w = di.w * xv.w;
        Oin.x = (Ein.x >= ti.x) ? Ein.x : 0.0f;
        Oin.y = (Ein.y >= ti.y) ? Ein.y : 0.0f;
        Oin.z = (Ein.z >= ti.z) ? Ein.z : 0.0f;
        Oin.w = (Ein.w >= ti.w) ? Ein.w : 0.0f;
        out4[Bs * 2 + rowBase + t] = Ein;
        out4[Bs * 3 + rowBase + t] = Oin;
    }
    __syncthreads();    // all tile reads done

    // ---- h2o transpose buffer (reuse tile region; stride 9 floats) ----
    s[5440 + (r +  0) * 9 + q] = h2o0;
    s[5440 + (r + 32) * 9 + q] = h2o1;
    s[5440 + (r + 64) * 9 + q] = h2o2;
    s[5440 + (r + 96) * 9 + q] = h2o3;

    // ---- E_hid / O_hid: direct global (no LDS), overlaps the hbuf sync ----
    {
        const float4 p0  = ws4[1360 + wq], p1  = ws4[1360 + wq + 1];   // a^4
        const float4 qv0 = ws4[1376 + wq], qv1 = ws4[1376 + wq + 1];   // sum a^i
        const float4 th0 = ws4[1392 + wq], th1 = ws4[1392 + wq + 1];   // th_hid
        const float4* gE0 = (const float4*)hidE0;
        #pragma unroll
        for (int i = 0; i < NR; ++i) {
            const size_t rho = rowBase + r + 32 * i;
            const float4 e0a = gE0[rho * 16 + wq];
            const float4 e0b = gE0[rho * 16 + wq + 1];
            const float4 Ia = (i == 0) ? I0a : (i == 1) ? I1a : (i == 2) ? I2a : I3a;
            const float4 Ib = (i == 0) ? I0b : (i == 1) ? I1b : (i == 2) ? I2b : I3b;
            float4 Ea, Eb, Oa, Ob;
            Ea.x = fmaf(p0.x, e0a.x, qv0.x * Ia.x);
            Ea.y = fmaf(p0.y, e0a.y, qv0.y * Ia.y);
            Ea.z = fmaf(p0.z, e0a.z, qv0.z * Ia.z);
            Ea.w = fmaf(p0.w, e0a.w, qv0.w * Ia.w);
            Eb.x = fmaf(p1.x, e0b.x, qv1.x * Ib.x);
            Eb.y = fmaf(p1.y, e0b.y, qv1.y * Ib.y);
            Eb.z = fmaf(p1.z, e0b.z, qv1.z * Ib.z);
            Eb.w = fmaf(p1.w, e0b.w, qv1.w * Ib.w);
            Oa.x = (Ea.x >= th0.x) ? Ea.x : 0.0f;
            Oa.y = (Ea.y >= th0.y) ? Ea.y : 0.0f;
            Oa.z = (Ea.z >= th0.z) ? Ea.z : 0.0f;
            Oa.w = (Ea.w >= th0.w) ? Ea.w : 0.0f;
            Ob.x = (Eb.x >= th1.x) ? Eb.x : 0.0f;
            Ob.y = (Eb.y >= th1.y) ? Eb.y : 0.0f;
            Ob.z = (Eb.z >= th1.z) ? Eb.z : 0.0f;
            Ob.w = (Eb.w >= th1.w) ? Eb.w : 0.0f;
            out4[Bs * 4  + rho * 16 + wq]     = Ea;
            out4[Bs * 4  + rho * 16 + wq + 1] = Eb;
            out4[Bs * 20 + rho * 16 + wq]     = Oa;
            out4[Bs * 20 + rho * 16 + wq + 1] = Ob;
        }
    }
    __syncthreads();    // hbuf complete

    // ---- output layer: coop over [128][8] region, dense f4 I/O ----
    {
        const int rl = t >> 1, c0 = (t & 1) * 4;
        const int hb = 5440 + rl * 9 + c0;
        const float h0 = s[hb + 0], h1 = s[hb + 1], h2 = s[hb + 2], h3 = s[hb + 3];
        const float4 e0  = ((const float4*)outE0)[rowBase * 2 + t];
        const float4 dec = ws4[1410 + (t & 1)];
        const float4 tho = ws4[1412 + (t & 1)];
        float4 Eo, act, Oo;
        Eo.x = fmaf(dec.x, e0.x, h0);
        Eo.y = fmaf(dec.y, e0.y, h1);
        Eo.z = fmaf(dec.z, e0.z, h2);
        Eo.w = fmaf(dec.w, e0.w, h3);
        act.x = tanhf(Eo.x); act.y = tanhf(Eo.y); act.z = tanhf(Eo.z); act.w = tanhf(Eo.w);
        Oo.x = (Eo.x >= tho.x) ? Eo.x : 0.0f;
        Oo.y = (Eo.y >= tho.y) ? Eo.y : 0.0f;
        Oo.z = (Eo.z >= tho.z) ? Eo.z : 0.0f;
        Oo.w = (Eo.w >= tho.w) ? Eo.w : 0.0f;
        out4[rowBase * 2 + t]           = act;
        out4[Bs * 36 + rowBase * 2 + t] = Eo;
        out4[Bs * 38 + rowBase * 2 + t] = Oo;
    }
}

extern "C" void kernel_launch(void* const* d_in, const int* in_sizes, int n_in,
                              void* d_out, int out_size, void* d_ws, size_t ws_size,
                              hipStream_t stream) {
    (void)n_in; (void)out_size; (void)ws_size;
    const float* x        = (const float*)d_in[0];
    const float* hidE0    = (const float*)d_in[1];
    const float* hidO0    = (const float*)d_in[2];
    const float* outE0    = (const float*)d_in[3];
    // d_in[4] (out_O0) unused by the reference
    const float* w_in2hid = (const float*)d_in[5];
    const float* w_hid_IN = (const float*)d_in[6];
    const float* w_hid_EX = (const float*)d_in[7];
    const float* w_hid2out= (const float*)d_in[8];
    const float* gj_w     = (const float*)d_in[9];
    const float* th_in    = (const float*)d_in[10];
    const float* dec_in   = (const float*)d_in[11];
    const float* th_hid   = (const float*)d_in[12];
    const float* dec_hid  = (const float*)d_in[13];
    const float* th_out   = (const float*)d_in[14];
    const float* dec_out  = (const float*)d_in[15];
    const int*   gj_src   = (const int*)d_in[16];
    const int*   gj_dst   = (const int*)d_in[17];
    float* out = (float*)d_out;
    float* ws  = (float*)d_ws;

    const int B = in_sizes[0] / 4;   // 262144, multiple of 128

    twc_prep<<<1, NT, 0, stream>>>(
        w_in2hid, w_hid_IN, w_hid_EX, w_hid2out, gj_w,
        th_in, dec_in, th_hid, dec_hid, th_out, dec_out,
        gj_src, gj_dst, ws);

    twc_main<<<B / RPB, NT, 0, stream>>>(x, hidE0, hidO0, outE0, ws, out, B);
}